// Round 4
// baseline (596.285 us; speedup 1.0000x reference)
//
#include <hip/hip_runtime.h>

#define NF 128
#define NR 6

// direct global->LDS DMA, 16B per lane; lds dest is wave-uniform base + lane*16
__device__ __forceinline__ void gload16(const float* g, float* l) {
    __builtin_amdgcn_global_load_lds(
        (const __attribute__((address_space(1))) unsigned int*)g,
        (__attribute__((address_space(3))) unsigned int*)l, 16, 0, 0);
}

// ---------------------------------------------------------------------------
// Pass 1: histogram of atom indices.
// ---------------------------------------------------------------------------
__global__ __launch_bounds__(256) void hist_kernel(
    const int* __restrict__ idx, int* __restrict__ count, int E)
{
    int stride = gridDim.x * blockDim.x;
    for (int e = blockIdx.x * blockDim.x + threadIdx.x; e < E; e += stride)
        atomicAdd(&count[idx[e]], 1);
}

// ---------------------------------------------------------------------------
// Pass 2: exclusive scan, one dispatch, 256 blocks (redundant prefix).
// ---------------------------------------------------------------------------
#define SCAN_BLOCKS 256

__global__ __launch_bounds__(256) void scan_all_kernel(
    const int* __restrict__ count, int* __restrict__ offsets,
    int* __restrict__ cursor, int N)
{
    __shared__ int red[256];
    __shared__ int tile[256];
    const int b = blockIdx.x, t = threadIdx.x;
    const int chunk = (N + SCAN_BLOCKS - 1) / SCAN_BLOCKS;
    const int lo = b * chunk;
    const int hi = min(lo + chunk, N);

    int s = 0;
    for (int i = t; i < lo; i += 256) s += count[i];
    red[t] = s;
    __syncthreads();
    for (int d = 128; d > 0; d >>= 1) {
        if (t < d) red[t] += red[t + d];
        __syncthreads();
    }
    int base = red[0];

    for (int p = lo; p < hi; p += 256) {
        int v = (p + t < hi) ? count[p + t] : 0;
        tile[t] = v;
        __syncthreads();
        for (int d = 1; d < 256; d <<= 1) {
            int u = (t >= d) ? tile[t - d] : 0;
            __syncthreads();
            tile[t] += u;
            __syncthreads();
        }
        if (p + t < hi) {
            int excl = base + tile[t] - v;
            offsets[p + t] = excl;
            cursor[p + t]  = excl;
            if (p + t == N - 1) offsets[N] = excl + v;
        }
        base += tile[255];
        __syncthreads();
    }
}

// ---------------------------------------------------------------------------
// Pass 3: reorder edge ids + rbf payload into segment order.
// ---------------------------------------------------------------------------
__global__ __launch_bounds__(256) void reorder_kernel(
    const int* __restrict__ idx, const float* __restrict__ rbf,
    int* __restrict__ cursor, int* __restrict__ sorted,
    float* __restrict__ srbf, int E)
{
    long stride = (long)gridDim.x * blockDim.x;
    for (long e = blockIdx.x * blockDim.x + threadIdx.x; e < E; e += stride) {
        int a = idx[e];
        int pos = atomicAdd(&cursor[a], 1);
        sorted[pos] = (int)e;
        const float2* rp = (const float2*)(rbf + e * NR);
        float2 r0 = rp[0], r1 = rp[1], r2 = rp[2];
        float2* dp = (float2*)(srbf + (long)pos * NR);
        dp[0] = r0; dp[1] = r1; dp[2] = r2;
    }
}

// ---------------------------------------------------------------------------
// Pass 4: fused gather + rbf projection + per-atom MLP.
// Block = 256 = 4 waves, 16 atoms/block; ONE atom per wave x4 sequential.
// Per batch of 16 edges: 8x global_load_lds (2 edge rows each, 8KB staged),
// rbf batch (96 floats) prefetched into registers (shfl-broadcast per edge),
// vmcnt(0), then process from LDS. Lane owns features 2*lane, 2*lane+1.
// Then swish -> sb, layer1 with W1 transposed in LDS, shfl-reduce layer2.
// ---------------------------------------------------------------------------
__global__ __launch_bounds__(256, 2) void gather_mlp_kernel(
    const float* __restrict__ m, const int* __restrict__ offsets,
    const int* __restrict__ sorted, const float* __restrict__ srbf,
    const float* __restrict__ W_rbf, const float* __restrict__ W1,
    const float* __restrict__ b1, const float* __restrict__ W2,
    const float* __restrict__ b2, float* __restrict__ out, int N, int E)
{
    __shared__ float W1t[128][68];     // 34.8 KB transposed W1 (padded)
    __shared__ float stg[4][16 * NF];  // 32 KB: per-wave 16-edge m staging
    __shared__ float sb[4][4][132];    // 8.4 KB swish-ed atom features

    const int t = threadIdx.x;
    const int lane = t & 63;
    const int w = t >> 6;

    // stage W1 transposed (vectorized)
    for (int k4 = t; k4 < 64 * 128 / 4; k4 += 256) {
        int k = k4 * 4;
        int j = k >> 7, f = k & 127;
        float4 v = *(const float4*)(W1 + k);
        W1t[f + 0][j] = v.x; W1t[f + 1][j] = v.y;
        W1t[f + 2][j] = v.z; W1t[f + 3][j] = v.w;
    }

    // per-lane W_rbf rows for features 2*lane, 2*lane+1
    float wr0[NR], wr1[NR];
#pragma unroll
    for (int r = 0; r < NR; ++r) {
        wr0[r] = W_rbf[(2 * lane + 0) * NR + r];
        wr1[r] = W_rbf[(2 * lane + 1) * NR + r];
    }

    float* stgw = stg[w];

    for (int ta = 0; ta < 4; ++ta) {
        const int n = blockIdx.x * 16 + w * 4 + ta;
        int beg = 0, end = 0;
        if (n < N) { beg = offsets[n]; end = offsets[n + 1]; }
        float acc0 = 0.f, acc1 = 0.f;
        int eid = 0;

        for (int p0 = beg; p0 < end; p0 += 16) {
            const int rel = p0 - beg;
            const int cnt = min(end - p0, 16);
            if ((rel & 63) == 0)
                eid = (p0 + lane < end) ? sorted[p0 + lane] : 0;
            const int base = rel & 63;

            // stage m rows: instruction k covers edges 2k (lanes 0-31) and
            // 2k+1 (lanes 32-63) -> stgw[(2k)*128..], stgw[(2k+1)*128..]
            for (int k = 0; 2 * k < cnt; ++k) {
                int e0 = __shfl(eid, base + 2 * k);
                int e1 = (2 * k + 1 < cnt) ? __shfl(eid, base + 2 * k + 1) : e0;
                int e = (lane < 32) ? e0 : e1;
                gload16(m + (long)e * NF + (lane & 31) * 4, stgw + k * 256);
            }

            // batch rbf: 96 floats in lanes 0..47 (float2 each), coalesced
            long ri = (long)p0 * NR + 2 * min(lane, 47);
            if (ri > (long)E * NR - 2) ri = (long)E * NR - 2;
            float2 rp = *(const float2*)(srbf + ri);

            asm volatile("s_waitcnt vmcnt(0)" ::: "memory");
            __builtin_amdgcn_sched_barrier(0);

            for (int j = 0; j < cnt; ++j) {
                float2 mv = *(const float2*)(stgw + j * NF + 2 * lane);
                float q0 = __shfl(rp.x, 3 * j + 0), q1 = __shfl(rp.y, 3 * j + 0);
                float q2 = __shfl(rp.x, 3 * j + 1), q3 = __shfl(rp.y, 3 * j + 1);
                float q4 = __shfl(rp.x, 3 * j + 2), q5 = __shfl(rp.y, 3 * j + 2);
                float f0 = q0 * wr0[0], f1 = q0 * wr1[0];
                f0 = fmaf(q1, wr0[1], f0); f1 = fmaf(q1, wr1[1], f1);
                f0 = fmaf(q2, wr0[2], f0); f1 = fmaf(q2, wr1[2], f1);
                f0 = fmaf(q3, wr0[3], f0); f1 = fmaf(q3, wr1[3], f1);
                f0 = fmaf(q4, wr0[4], f0); f1 = fmaf(q4, wr1[4], f1);
                f0 = fmaf(q5, wr0[5], f0); f1 = fmaf(q5, wr1[5], f1);
                acc0 = fmaf(mv.x, f0, acc0);
                acc1 = fmaf(mv.y, f1, acc1);
            }
        }

        float s0 = acc0 / (1.f + __expf(-acc0));
        float s1 = acc1 / (1.f + __expf(-acc1));
        *(float2*)&sb[w][ta][2 * lane] = make_float2(s0, s1);
    }

    __syncthreads();

    // layer 1: 16-lane group ag = atom (0..3 of this wave), lane lj owns
    // outputs 4*lj..4*lj+3
    const int ag = lane >> 4;
    const int lj = lane & 15;

    float4 bv = *(const float4*)(b1 + 4 * lj);
    float h0 = bv.x, h1 = bv.y, h2 = bv.z, h3 = bv.w;

    for (int f = 0; f < 128; f += 4) {
        float4 sv = *(const float4*)&sb[w][ag][f];
        float4 w0 = *(const float4*)&W1t[f + 0][4 * lj];
        float4 w1v = *(const float4*)&W1t[f + 1][4 * lj];
        float4 w2v = *(const float4*)&W1t[f + 2][4 * lj];
        float4 w3v = *(const float4*)&W1t[f + 3][4 * lj];
        h0 = fmaf(sv.x, w0.x, h0);  h1 = fmaf(sv.x, w0.y, h1);
        h2 = fmaf(sv.x, w0.z, h2);  h3 = fmaf(sv.x, w0.w, h3);
        h0 = fmaf(sv.y, w1v.x, h0); h1 = fmaf(sv.y, w1v.y, h1);
        h2 = fmaf(sv.y, w1v.z, h2); h3 = fmaf(sv.y, w1v.w, h3);
        h0 = fmaf(sv.z, w2v.x, h0); h1 = fmaf(sv.z, w2v.y, h1);
        h2 = fmaf(sv.z, w2v.z, h2); h3 = fmaf(sv.z, w2v.w, h3);
        h0 = fmaf(sv.w, w3v.x, h0); h1 = fmaf(sv.w, w3v.y, h1);
        h2 = fmaf(sv.w, w3v.z, h2); h3 = fmaf(sv.w, w3v.w, h3);
    }

    float4 w2 = *(const float4*)(W2 + 4 * lj);
    float r = (h0 / (1.f + __expf(-h0))) * w2.x
            + (h1 / (1.f + __expf(-h1))) * w2.y
            + (h2 / (1.f + __expf(-h2))) * w2.z
            + (h3 / (1.f + __expf(-h3))) * w2.w;

    r += __shfl_xor(r, 1);
    r += __shfl_xor(r, 2);
    r += __shfl_xor(r, 4);
    r += __shfl_xor(r, 8);

    int n = blockIdx.x * 16 + w * 4 + ag;
    if (lj == 0 && n < N) out[n] = r + b2[0];
}

extern "C" void kernel_launch(void* const* d_in, const int* in_sizes, int n_in,
                              void* d_out, int out_size, void* d_ws, size_t ws_size,
                              hipStream_t stream) {
    const float* m     = (const float*)d_in[0];
    const float* rbf   = (const float*)d_in[1];
    const int*   idx   = (const int*)d_in[2];
    const float* W_rbf = (const float*)d_in[4];
    const float* W1    = (const float*)d_in[5];
    const float* b1    = (const float*)d_in[6];
    const float* W2    = (const float*)d_in[7];
    const float* b2    = (const float*)d_in[8];
    float* out = (float*)d_out;

    const int E = in_sizes[2];   // one atom index per edge
    const int N = out_size;      // out is [N, 1]

    // workspace layout (all segment starts 8B-aligned)
    int* count   = (int*)d_ws;                        // N
    int* offsets = count + N;                         // N+1
    int* cursor  = offsets + ((N + 2) & ~1);          // N
    int* sorted  = cursor + N;                        // E
    float* srbf  = (float*)(sorted + ((E + 1) & ~1)); // 6E floats

    hipMemsetAsync(count, 0, (size_t)N * sizeof(int), stream);

    hist_kernel<<<2048, 256, 0, stream>>>(idx, count, E);
    scan_all_kernel<<<SCAN_BLOCKS, 256, 0, stream>>>(count, offsets, cursor, N);
    reorder_kernel<<<2048, 256, 0, stream>>>(idx, rbf, cursor, sorted, srbf, E);
    gather_mlp_kernel<<<(N + 15) / 16, 256, 0, stream>>>(
        m, offsets, sorted, srbf, W_rbf, W1, b1, W2, b2, out, N, E);
}

// Round 5
// 557.450 us; speedup vs baseline: 1.0697x; 1.0697x over previous
//
#include <hip/hip_runtime.h>

#define NF 128
#define NR 6

// ---------------------------------------------------------------------------
// Pass 1: histogram of atom indices.
// ---------------------------------------------------------------------------
__global__ __launch_bounds__(256) void hist_kernel(
    const int* __restrict__ idx, int* __restrict__ count, int E)
{
    int stride = gridDim.x * blockDim.x;
    for (int e = blockIdx.x * blockDim.x + threadIdx.x; e < E; e += stride)
        atomicAdd(&count[idx[e]], 1);
}

// ---------------------------------------------------------------------------
// Pass 2: exclusive scan, one dispatch, 256 blocks (redundant prefix).
// ---------------------------------------------------------------------------
#define SCAN_BLOCKS 256

__global__ __launch_bounds__(256) void scan_all_kernel(
    const int* __restrict__ count, int* __restrict__ offsets,
    int* __restrict__ cursor, int N)
{
    __shared__ int red[256];
    __shared__ int tile[256];
    const int b = blockIdx.x, t = threadIdx.x;
    const int chunk = (N + SCAN_BLOCKS - 1) / SCAN_BLOCKS;
    const int lo = b * chunk;
    const int hi = min(lo + chunk, N);

    int s = 0;
    for (int i = t; i < lo; i += 256) s += count[i];
    red[t] = s;
    __syncthreads();
    for (int d = 128; d > 0; d >>= 1) {
        if (t < d) red[t] += red[t + d];
        __syncthreads();
    }
    int base = red[0];

    for (int p = lo; p < hi; p += 256) {
        int v = (p + t < hi) ? count[p + t] : 0;
        tile[t] = v;
        __syncthreads();
        for (int d = 1; d < 256; d <<= 1) {
            int u = (t >= d) ? tile[t - d] : 0;
            __syncthreads();
            tile[t] += u;
            __syncthreads();
        }
        if (p + t < hi) {
            int excl = base + tile[t] - v;
            offsets[p + t] = excl;
            cursor[p + t]  = excl;
            if (p + t == N - 1) offsets[N] = excl + v;
        }
        base += tile[255];
        __syncthreads();
    }
}

// ---------------------------------------------------------------------------
// Pass 3: reorder edge ids + rbf payload into segment order.
// ---------------------------------------------------------------------------
__global__ __launch_bounds__(256) void reorder_kernel(
    const int* __restrict__ idx, const float* __restrict__ rbf,
    int* __restrict__ cursor, int* __restrict__ sorted,
    float* __restrict__ srbf, int E)
{
    long stride = (long)gridDim.x * blockDim.x;
    for (long e = blockIdx.x * blockDim.x + threadIdx.x; e < E; e += stride) {
        int a = idx[e];
        int pos = atomicAdd(&cursor[a], 1);
        sorted[pos] = (int)e;
        const float2* rp = (const float2*)(rbf + e * NR);
        float2 r0 = rp[0], r1 = rp[1], r2 = rp[2];
        float2* dp = (float2*)(srbf + (long)pos * NR);
        dp[0] = r0; dp[1] = r1; dp[2] = r2;
    }
}

// ---------------------------------------------------------------------------
// Pass 4: gather + rbf projection + swish -> af[N][128] (global).
// One atom per WAVE (beg/end wave-uniform -> uniform control flow). Lane owns
// features 2*lane, 2*lane+1 (float2 m loads, 512B/edge/wave). Edge batches of
// 8 with register double-buffered m prefetch (4KB in flight per wave). Edge
// ids come from a 64-deep shfl cache with rolling reload. No LDS.
// ---------------------------------------------------------------------------
__global__ __launch_bounds__(256, 3) void gather_kernel(
    const float* __restrict__ m, const int* __restrict__ offsets,
    const int* __restrict__ sorted, const float* __restrict__ srbf,
    const float* __restrict__ W_rbf, float* __restrict__ af, int N)
{
    const int t = threadIdx.x;
    const int lane = t & 63;
    const int w = t >> 6;

    // per-lane W_rbf rows for features 2*lane, 2*lane+1
    float wr0[NR], wr1[NR];
#pragma unroll
    for (int r = 0; r < NR; ++r) {
        wr0[r] = W_rbf[(2 * lane + 0) * NR + r];
        wr1[r] = W_rbf[(2 * lane + 1) * NR + r];
    }

    for (int ta = 0; ta < 4; ++ta) {
        const int n = blockIdx.x * 16 + w * 4 + ta;
        if (n >= N) break;
        const int beg = offsets[n];
        const int end = offsets[n + 1];
        float acc0 = 0.f, acc1 = 0.f;

        int cbase = beg;
        int eid = (cbase + lane < end) ? sorted[cbase + lane] : 0;

        float2 mv_cur[8], mv_nxt[8];
        // prologue: batch 0 m loads
        {
            const int cnt0 = min(end - beg, 8);
#pragma unroll
            for (int k = 0; k < 8; ++k) {
                int e = __shfl(eid, (k < cnt0) ? k : 0);
                mv_cur[k] = *(const float2*)(m + (long)e * NF + 2 * lane);
            }
        }

        for (int p = beg; p < end; p += 8) {
            const int cnt = min(end - p, 8);

            // current batch rbf rows (wave-uniform addresses)
            float2 rv[8][3];
#pragma unroll
            for (int k = 0; k < 8; ++k) {
                long pe = p + ((k < cnt) ? k : 0);
                const float2* rp = (const float2*)(srbf + pe * NR);
                rv[k][0] = rp[0]; rv[k][1] = rp[1]; rv[k][2] = rp[2];
            }

            // prefetch next batch m (rolling eid cache)
            const int pn = p + 8;
            if (pn < end) {
                if (pn - cbase >= 57) {
                    cbase = pn;
                    eid = (cbase + lane < end) ? sorted[cbase + lane] : 0;
                }
                const int cn = min(end - pn, 8);
#pragma unroll
                for (int k = 0; k < 8; ++k) {
                    int off = pn - cbase + ((k < cn) ? k : 0);
                    int e = __shfl(eid, off);
                    mv_nxt[k] = *(const float2*)(m + (long)e * NF + 2 * lane);
                }
            }

            // compute current batch
#pragma unroll
            for (int k = 0; k < 8; ++k) {
                if (k < cnt) {
                    float q0 = rv[k][0].x, q1 = rv[k][0].y;
                    float q2 = rv[k][1].x, q3 = rv[k][1].y;
                    float q4 = rv[k][2].x, q5 = rv[k][2].y;
                    float f0 = q0 * wr0[0], f1 = q0 * wr1[0];
                    f0 = fmaf(q1, wr0[1], f0); f1 = fmaf(q1, wr1[1], f1);
                    f0 = fmaf(q2, wr0[2], f0); f1 = fmaf(q2, wr1[2], f1);
                    f0 = fmaf(q3, wr0[3], f0); f1 = fmaf(q3, wr1[3], f1);
                    f0 = fmaf(q4, wr0[4], f0); f1 = fmaf(q4, wr1[4], f1);
                    f0 = fmaf(q5, wr0[5], f0); f1 = fmaf(q5, wr1[5], f1);
                    acc0 = fmaf(mv_cur[k].x, f0, acc0);
                    acc1 = fmaf(mv_cur[k].y, f1, acc1);
                }
            }
#pragma unroll
            for (int k = 0; k < 8; ++k) mv_cur[k] = mv_nxt[k];
        }

        float s0 = acc0 / (1.f + __expf(-acc0));
        float s1 = acc1 / (1.f + __expf(-acc1));
        *(float2*)(af + (long)n * NF + 2 * lane) = make_float2(s0, s1);
    }
}

// ---------------------------------------------------------------------------
// Pass 5: per-atom MLP. Block = 256 = 4 waves, 64 atoms/block (16 per wave).
// Lane (ag, lj): ag = lane>>4 picks 4 atoms, lj = lane&15 owns outputs
// 4*lj..4*lj+3. W1t reads are wave-uniform (broadcast, conflict-free) so W1t
// LDS traffic amortizes over 16 atoms/wave. sb reads uniform per 16-lane
// group. 64 fma per f-step-of-4.
// ---------------------------------------------------------------------------
__global__ __launch_bounds__(256, 2) void mlp_kernel(
    const float* __restrict__ af, const float* __restrict__ W1,
    const float* __restrict__ b1, const float* __restrict__ W2,
    const float* __restrict__ b2, float* __restrict__ out, int N)
{
    __shared__ float W1t[128][68];   // 34.8 KB transposed W1
    __shared__ float sb[64][132];    // 33.8 KB swish-ed atom features

    const int t = threadIdx.x;

    // stage W1 transposed
    for (int k4 = t; k4 < 2048; k4 += 256) {
        int k = k4 * 4;
        int j = k >> 7, f = k & 127;
        float4 v = *(const float4*)(W1 + k);
        W1t[f + 0][j] = v.x; W1t[f + 1][j] = v.y;
        W1t[f + 2][j] = v.z; W1t[f + 3][j] = v.w;
    }

    // stage 64 atom rows (already swish-ed by gather), coalesced
    const int nb = blockIdx.x * 64;
    for (int k4 = t; k4 < 2048; k4 += 256) {
        int row = k4 >> 5, col = (k4 & 31) * 4;
        int n = nb + row;
        float4 v = make_float4(0.f, 0.f, 0.f, 0.f);
        if (n < N) v = *(const float4*)(af + (long)n * NF + col);
        *(float4*)&sb[row][col] = v;
    }
    __syncthreads();

    const int lane = t & 63, w = t >> 6;
    const int ag = lane >> 4, lj = lane & 15;
    const int abase = w * 16 + ag * 4;

    float4 bv = *(const float4*)(b1 + 4 * lj);
    float h[4][4];
#pragma unroll
    for (int i = 0; i < 4; ++i) {
        h[i][0] = bv.x; h[i][1] = bv.y; h[i][2] = bv.z; h[i][3] = bv.w;
    }

    for (int f = 0; f < 128; f += 4) {
        float4 w0  = *(const float4*)&W1t[f + 0][4 * lj];
        float4 w1v = *(const float4*)&W1t[f + 1][4 * lj];
        float4 w2v = *(const float4*)&W1t[f + 2][4 * lj];
        float4 w3v = *(const float4*)&W1t[f + 3][4 * lj];
#pragma unroll
        for (int i = 0; i < 4; ++i) {
            float4 sv = *(const float4*)&sb[abase + i][f];
            h[i][0] = fmaf(sv.w, w3v.x, fmaf(sv.z, w2v.x, fmaf(sv.y, w1v.x, fmaf(sv.x, w0.x, h[i][0]))));
            h[i][1] = fmaf(sv.w, w3v.y, fmaf(sv.z, w2v.y, fmaf(sv.y, w1v.y, fmaf(sv.x, w0.y, h[i][1]))));
            h[i][2] = fmaf(sv.w, w3v.z, fmaf(sv.z, w2v.z, fmaf(sv.y, w1v.z, fmaf(sv.x, w0.z, h[i][2]))));
            h[i][3] = fmaf(sv.w, w3v.w, fmaf(sv.z, w2v.w, fmaf(sv.y, w1v.w, fmaf(sv.x, w0.w, h[i][3]))));
        }
    }

    float4 w2v4 = *(const float4*)(W2 + 4 * lj);
    float b2v = b2[0];

    float c0, c1, c2, c3;
    {
        float v;
        v  = (h[0][0] / (1.f + __expf(-h[0][0]))) * w2v4.x;
        v += (h[0][1] / (1.f + __expf(-h[0][1]))) * w2v4.y;
        v += (h[0][2] / (1.f + __expf(-h[0][2]))) * w2v4.z;
        v += (h[0][3] / (1.f + __expf(-h[0][3]))) * w2v4.w;
        c0 = v;
        v  = (h[1][0] / (1.f + __expf(-h[1][0]))) * w2v4.x;
        v += (h[1][1] / (1.f + __expf(-h[1][1]))) * w2v4.y;
        v += (h[1][2] / (1.f + __expf(-h[1][2]))) * w2v4.z;
        v += (h[1][3] / (1.f + __expf(-h[1][3]))) * w2v4.w;
        c1 = v;
        v  = (h[2][0] / (1.f + __expf(-h[2][0]))) * w2v4.x;
        v += (h[2][1] / (1.f + __expf(-h[2][1]))) * w2v4.y;
        v += (h[2][2] / (1.f + __expf(-h[2][2]))) * w2v4.z;
        v += (h[2][3] / (1.f + __expf(-h[2][3]))) * w2v4.w;
        c2 = v;
        v  = (h[3][0] / (1.f + __expf(-h[3][0]))) * w2v4.x;
        v += (h[3][1] / (1.f + __expf(-h[3][1]))) * w2v4.y;
        v += (h[3][2] / (1.f + __expf(-h[3][2]))) * w2v4.z;
        v += (h[3][3] / (1.f + __expf(-h[3][3]))) * w2v4.w;
        c3 = v;
    }
#pragma unroll
    for (int d = 1; d < 16; d <<= 1) {
        c0 += __shfl_xor(c0, d);
        c1 += __shfl_xor(c1, d);
        c2 += __shfl_xor(c2, d);
        c3 += __shfl_xor(c3, d);
    }

    if (lj < 4) {
        int n = nb + abase + lj;
        float val = (lj == 0) ? c0 : (lj == 1) ? c1 : (lj == 2) ? c2 : c3;
        if (n < N) out[n] = val + b2v;
    }
}

extern "C" void kernel_launch(void* const* d_in, const int* in_sizes, int n_in,
                              void* d_out, int out_size, void* d_ws, size_t ws_size,
                              hipStream_t stream) {
    const float* m     = (const float*)d_in[0];
    const float* rbf   = (const float*)d_in[1];
    const int*   idx   = (const int*)d_in[2];
    const float* W_rbf = (const float*)d_in[4];
    const float* W1    = (const float*)d_in[5];
    const float* b1    = (const float*)d_in[6];
    const float* W2    = (const float*)d_in[7];
    const float* b2    = (const float*)d_in[8];
    float* out = (float*)d_out;

    const int E = in_sizes[2];   // one atom index per edge
    const int N = out_size;      // out is [N, 1]

    // workspace layout (all segment starts 8B-aligned)
    int* count   = (int*)d_ws;                         // N
    int* offsets = count + N;                          // N+1
    int* cursor  = offsets + ((N + 2) & ~1);           // N
    int* sorted  = cursor + N;                         // E
    float* srbf  = (float*)(sorted + ((E + 1) & ~1));  // 6E floats
    float* af    = srbf + (long)E * NR;                // N*128 floats (51.2MB)

    hipMemsetAsync(count, 0, (size_t)N * sizeof(int), stream);

    hist_kernel<<<2048, 256, 0, stream>>>(idx, count, E);
    scan_all_kernel<<<SCAN_BLOCKS, 256, 0, stream>>>(count, offsets, cursor, N);
    reorder_kernel<<<2048, 256, 0, stream>>>(idx, rbf, cursor, sorted, srbf, E);
    gather_kernel<<<(N + 15) / 16, 256, 0, stream>>>(
        m, offsets, sorted, srbf, W_rbf, af, N);
    mlp_kernel<<<(N + 63) / 64, 256, 0, stream>>>(af, W1, b1, W2, b2, out, N);
}